// Round 17
// baseline (230.548 us; speedup 1.0000x reference)
//
#include <hip/hip_runtime.h>
#include <utility>

#define N_SAMP   4410000
#define WSZ      441
#define NC       10000
#define NB       250
#define LB       40           // NB*LB == NC
#define HB       20           // half-block flush granularity
#define TILEF    (LB*WSZ)     // 17640 floats = per-block fb tile (70.6 KB)
#define RD       32           // Horner chunk size
#define TWO_PI_F 6.28318530717958647692f
#define FADE_START (N_SAMP - 256)
#define INV_SR   (1.0f/44100.0f)
#define INV441   (1.0f/441.0f)
#define MAGIC    0x5EEDF00Du

// workspace layout (floats)
#define WS_WT    0                          // 441 wavetable (fallback path only)
#define WS_SLOT(a) (448 + (a)*448)          // a = 0..NB-2: Vhat_a ([0..220]=Re, [224..444]=Im)
#define WS_FLAGS (448 + (NB-1)*448)         // NB u32 publish flags
#define WS_NEED  ((size_t)(WS_FLAGS + NB) * sizeof(float))

static_assert(NB * LB == NC, "block decomposition");
static_assert(LB == 2*HB, "two flush phases");

// ---- compile-time loop unroll (forces static indices -> registers, rule #20) ----
template <class F, int... Is>
__device__ __forceinline__ void unroll_impl(F f, std::integer_sequence<int, Is...>) {
    (f(std::integral_constant<int, Is>{}), ...);
}
template <int N, class F>
__device__ __forceinline__ void unroll_for(F f) {
    unroll_impl(f, std::make_integer_sequence<int, N>{});
}

// hardware trig: v_sin_f32/v_cos_f32 — input in REVOLUTIONS (sin/cos(2*pi*x)).
__device__ __forceinline__ float hwsin(float rev) { return __builtin_amdgcn_sinf(rev); }
__device__ __forceinline__ float hwcos(float rev) { return __builtin_amdgcn_cosf(rev); }

// async global->LDS: lane l copies 16B from its gsrc to ldsbase + l*16 (wave-uniform base).
__device__ __forceinline__ void gl2lds16(const float* gsrc_lane, float* lds_base_uniform) {
    __builtin_amdgcn_global_load_lds(
        (const __attribute__((address_space(1))) void*)gsrc_lane,
        (__attribute__((address_space(3))) void*)lds_base_uniform,
        16, 0, 0);
}

// stage nfloats from g to l using 7 waves (448 threads); caller must __syncthreads() after.
__device__ __forceinline__ void stage_tile7(const float* __restrict__ g,
                                            float* __restrict__ l,
                                            int nfloats, int tid) {
    const int wave = tid >> 6, lane = tid & 63;
    const int nfull = nfloats >> 8;              // 256-float (1 KiB) chunks
    for (int c = wave; c < nfull; c += 7)
        gl2lds16(g + (c << 8) + lane*4, l + (c << 8));
    const int rem = nfloats & 255;
    if (rem && wave == 0 && lane*4 < rem) {
        const int base = nfull << 8;
        gl2lds16(g + base + lane*4, l + base);
    }
}

__device__ __forceinline__ void bq_coefs(float f, float q,
    float& b0, float& b1, float& b2, float& a1, float& a2)
{
    float w0 = TWO_PI_F * f / 44100.0f;
    float cw = cosf(w0), sw = sinf(w0);
    float al = sw / (2.0f * q);
    float a0 = 1.0f + al;
    b0 = ((1.0f - cw) * 0.5f) / a0;
    b1 = (1.0f - cw) / a0;
    b2 = ((1.0f - cw) * 0.5f) / a0;
    a1 = (-2.0f * cw) / a0;
    a2 = (1.0f - al) / a0;
}

// serial biquad pair (fallback kernel only)
__device__ __forceinline__ void run_biquads(const float* __restrict__ noise,
    float lpf, float lpq, float f2, float* dst)
{
    float c10,c11,c12,c13,c14, c20,c21,c22,c23,c24;
    bq_coefs(lpf, lpq, c10,c11,c12,c13,c14);
    bq_coefs(f2, 0.707f, c20,c21,c22,c23,c24);
    float s11=0.f,s12=0.f,s21=0.f,s22=0.f;
    for (int m = 0; m < WSZ; ++m) {
        float x  = noise[m];
        float y1 = c10*x + s11;
        s11 = c11*x - c13*y1 + s12;
        s12 = c12*x - c14*y1;
        float y2 = c20*y1 + s21;
        s21 = c21*y1 - c23*y2 + s22;
        s22 = c22*y1 - c24*y2;
        dst[m] = y2;
    }
}

// redundant per-wave MLP: lane computes hid cols lane, lane+64; shfl_xor reduce -> lat[5]
__device__ __forceinline__ void mlp_latents(
    const float* __restrict__ h, const float* __restrict__ W1,
    const float* __restrict__ b1v, const float* __restrict__ W2,
    const float* __restrict__ b2v, int lane, float lat[5])
{
    float hc0 = b1v[lane], hc1 = b1v[lane + 64];
    #pragma unroll
    for (int i = 0; i < 9; ++i) {
        float hv = h[i];
        hc0 = fmaf(hv, W1[i*128 + lane], hc0);
        hc1 = fmaf(hv, W1[i*128 + lane + 64], hc1);
    }
    hc0 = fmaxf(hc0, 0.f); hc1 = fmaxf(hc1, 0.f);
    float part[5];
    #pragma unroll
    for (int m = 0; m < 5; ++m)
        part[m] = fmaf(hc0, W2[lane*5 + m], hc1 * W2[(lane+64)*5 + m]);
    #pragma unroll
    for (int off = 32; off > 0; off >>= 1) {
        #pragma unroll
        for (int m = 0; m < 5; ++m)
            part[m] += __shfl_xor(part[m], off);
    }
    #pragma unroll
    for (int m = 0; m < 5; ++m)
        lat[m] = fmaxf(part[m] + b2v[m], 0.f);
}

// wave-parallel biquad over 441 samples: lane l holds positions 7l..7l+6 (Kogge-Stone affine scan)
__device__ __forceinline__ void biquad_wave(const float xin[7], float yout[7],
    float f, float q, int l)
{
    float b0,b1,b2,a1,a2;
    bq_coefs(f, q, b0,b1,b2,a1,a2);
    const float t1c = b1 - a1*b0;
    const float t2c = b2 - a2*b0;
    float m00=1.f,m01=0.f,m10=0.f,m11=1.f;
    float cv0=0.f, cv1=0.f;
    #pragma unroll
    for (int k = 0; k < 7; ++k) {
        float x = xin[k];
        float n0 = -a1*cv0 + cv1 + t1c*x;
        float n1 = -a2*cv0 + t2c*x;
        cv0 = n0; cv1 = n1;
        float r00 = -a1*m00 + m10, r01 = -a1*m01 + m11;
        float r10 = -a2*m00,       r11 = -a2*m01;
        m00=r00; m01=r01; m10=r10; m11=r11;
    }
    #pragma unroll
    for (int d = 1; d < 64; d <<= 1) {
        int srcl = l - d; int s2 = srcl < 0 ? 0 : srcl;
        float pm00=__shfl(m00,s2), pm01=__shfl(m01,s2);
        float pm10=__shfl(m10,s2), pm11=__shfl(m11,s2);
        float pc0=__shfl(cv0,s2), pc1=__shfl(cv1,s2);
        if (srcl >= 0) {
            float nc0 = m00*pc0 + m01*pc1 + cv0;
            float nc1 = m10*pc0 + m11*pc1 + cv1;
            float n00 = m00*pm00 + m01*pm10;
            float n01 = m00*pm01 + m01*pm11;
            float n10 = m10*pm00 + m11*pm10;
            float n11 = m10*pm01 + m11*pm11;
            m00=n00; m01=n01; m10=n10; m11=n11; cv0=nc0; cv1=nc1;
        }
    }
    int esrc = (l == 0) ? 0 : l - 1;
    float e0 = __shfl(cv0, esrc);
    float e1 = __shfl(cv1, esrc);
    float s1  = (l == 0) ? 0.f : e0;
    float s2v = (l == 0) ? 0.f : e1;
    #pragma unroll
    for (int k = 0; k < 7; ++k) {
        float x = xin[k];
        float y = b0*x + s1;
        float ns1 = b1*x - a1*y + s2v;
        s2v = b2*x - a2*y;
        s1 = ns1;
        yout[k] = y;
    }
}

// ---------- 441-pt forward FFT (21x21 Cooley-Tukey), real input in v, modes 0..220 -> ws slot ----------
__device__ __forceinline__ void fft441_fwd(const float* v, float* Zr, float* Zi,
    const float* c441, const float* s441, float* ws_slot, int tid)
{
    if (tid < 441) {
        const int bq = tid / 21, c = tid - 21*bq;
        float yr = 0.f, yi = 0.f;
        int pm = 0;                                // (a*c) % 21
        #pragma unroll
        for (int a = 0; a < 21; ++a) {
            float x = v[21*a + bq];
            float cc = c441[21*pm], ss = s441[21*pm];
            yr = fmaf(x,  cc, yr);
            yi = fmaf(-x, ss, yi);
            pm += c; if (pm >= 21) pm -= 21;
        }
        const int bc = bq * c;                     // <= 400 < 441
        float cB = c441[bc], sB = s441[bc];
        Zr[c*21 + bq] = yr*cB + yi*sB;             // Z = Y * (cB - i sB)
        Zi[c*21 + bq] = yi*cB - yr*sB;
    }
    __syncthreads();
    if (tid < 441) {
        const int c = tid / 21, d = tid - 21*c;
        float xr = 0.f, xi = 0.f;
        int pm = 0;                                // (b*d) % 21
        const float* zr = Zr + c*21;
        const float* zi = Zi + c*21;
        #pragma unroll
        for (int bq = 0; bq < 21; ++bq) {
            float cc = c441[21*pm], ss = s441[21*pm];
            float gr = zr[bq], gi = zi[bq];
            xr = fmaf(gr, cc, fmaf(gi,  ss, xr));  // X += Z * (cc - i ss)
            xi = fmaf(gi, cc, fmaf(-gr, ss, xi));
            pm += d; if (pm >= 21) pm -= 21;
        }
        const int jm = c + 21*d;
        if (jm < 221) {
            ws_slot[jm]       = xr;
            ws_slot[224 + jm] = xi;
        }
    }
}

// ---------- 441-pt inverse FFT: full-spectrum S (conj-extended) -> real e_lds; scaled 1/441 ----------
__device__ __forceinline__ void fft441_inv(const float* SrF, const float* SiF,
    float* Hr, float* Hi, const float* c441, const float* s441,
    float* e_lds, int tid)
{
    if (tid < 441) {
        const int bq = tid / 21, c = tid - 21*bq;
        float gr = 0.f, gi = 0.f;
        int pm = 0;                                // (a*c) % 21
        #pragma unroll
        for (int a = 0; a < 21; ++a) {
            float sr = SrF[21*a + bq], si = SiF[21*a + bq];
            float cc = c441[21*pm], ss = s441[21*pm];
            gr = fmaf(sr, cc, fmaf(-si, ss, gr));  // G += S * (cc + i ss)
            gi = fmaf(sr, ss, fmaf( si, cc, gi));
            pm += c; if (pm >= 21) pm -= 21;
        }
        const int bc = bq * c;
        float cB = c441[bc], sB = s441[bc];
        Hr[c*21 + bq] = gr*cB - gi*sB;             // H = G * (cB + i sB)
        Hi[c*21 + bq] = gr*sB + gi*cB;
    }
    __syncthreads();
    if (tid < 441) {
        const int c = tid / 21, d = tid - 21*c;
        float acc = 0.f;
        int pm = 0;                                // (b*d) % 21
        const float* hr = Hr + c*21;
        const float* hi = Hi + c*21;
        #pragma unroll
        for (int bq = 0; bq < 21; ++bq) {
            float cc = c441[21*pm], ss = s441[21*pm];
            acc = fmaf(hr[bq], cc, fmaf(-hi[bq], ss, acc));  // Re(H * (cc + i ss))
            pm += d; if (pm >= 21) pm -= 21;
        }
        e_lds[c + 21*d] = acc * (1.0f/441.0f);
    }
}

// ================== fused single kernel (cooperative launch for residency; NO grid sync) ==================
// Phase 1: stage fb tile once + local recurrence + fwd FFT -> publish Vhat_b (release flag).
// Phase 2: per-block Horner (flag-gated chunks) + inverse FFT -> entry state.
// Phase 3: true recurrence over the SAME staged tile + env/fade/gain flush.
__global__ __launch_bounds__(448, 1) void k_all(
    const float* __restrict__ fb, const float* __restrict__ h,
    const float* __restrict__ noise, const float* __restrict__ W1,
    const float* __restrict__ b1v, const float* __restrict__ W2,
    const float* __restrict__ b2v, const float* __restrict__ lpcut,
    const float* __restrict__ t_in, const float* __restrict__ envp,
    const float* __restrict__ fade, float* __restrict__ out,
    float* __restrict__ ws)
{
    __shared__ __align__(16) float fbL[TILEF + 24];    // 70.7 KB, lives through all phases
    __shared__ float out_lds[HB*441];                  // 35.3 KB
    __shared__ __align__(16) float v_lds[448];
    __shared__ __align__(16) float e_lds[448];
    __shared__ __align__(16) float Ar[441], Ai[441];   // FFT stage scratch (Z fwd / H inv)
    __shared__ __align__(16) float SrF[441], SiF[441];
    __shared__ float c441[441], s441[441];
    unsigned* flags = (unsigned*)(ws + WS_FLAGS);
    const int b = blockIdx.x;                          // 0..NB-1
    const int tid = threadIdx.x;
    const bool w0 = tid < 64;
    const int j = tid;
    const bool act = w0 && (j < 63);
    const int i0 = b * LB;

    stage_tile7(fb + i0*WSZ, fbL, TILEF, tid);   // staged ONCE; reused in phase 3
    if (tid < 441) {
        float ph = (float)tid * INV441;
        c441[tid] = hwcos(ph);
        s441[tid] = hwsin(ph);
    }

    float lat[5];
    mlp_latents(h, W1, b1v, W2, b2v, tid & 63, lat);
    const float decay = fminf(fmaxf(lat[0]/10.0f + 0.9f, 0.9f), 0.999f);
    const float famt  = lat[3];
    const float gain  = lat[4];
    const float d2 = 0.5f * decay;
    const int src = (j == 0) ? 62 : j - 1;

    float cur[7];
    #pragma unroll
    for (int k = 0; k < 7; ++k) cur[k] = 0.f;
    if (w0 && b == 0) {
        const float lpf = fminf(fmaxf(lat[1]*44100.0f/4.0f, 100.0f), 22049.0f);
        const float lpq = fminf(fmaxf(lat[2], 0.1f), 0.999f);
        const float f2  = lpcut[0];
        float xin[7], y1[7], y2[7];
        #pragma unroll
        for (int k = 0; k < 7; ++k) xin[k] = act ? noise[7*j + k] : 0.f;
        biquad_wave(xin, y1, lpf, lpq, j);
        biquad_wave(y1, y2, f2, 0.707f, j);
        #pragma unroll
        for (int k = 0; k < 7; ++k) {
            cur[k] = act ? y2[k] : 0.f;
            if (act) e_lds[7*j + k] = y2[k];     // phase-3 entry state for block 0
        }
    }
    __syncthreads();                             // staging drained; tables ready

    // ---------------- phase 1: local recurrence + fwd FFT + publish (blocks 0..NB-2) ----------------
    if (b < NB-1) {
        if (w0) {
            unroll_for<LB>([&](auto I) {
                constexpr int i = decltype(I)::value;
                float x[7];
                #pragma unroll
                for (int k = 0; k < 7; ++k) {
                    float fv = act ? fbL[i*WSZ + 7*j + k] : 0.f;
                    x[k] = fmaf(famt, fv, cur[k]);
                }
                float x6p = __shfl(x[6], src);   // pos 7j-1; lane0 <- lane62 (pos 440)
                cur[0] = d2 * (x[0] + x6p);
                #pragma unroll
                for (int k = 1; k < 7; ++k)
                    cur[k] = d2 * (x[k] + x[k-1]);
            });
            if (act) {
                #pragma unroll
                for (int k = 0; k < 7; ++k) v_lds[7*j + k] = cur[k];
            }
        }
        __syncthreads();
        fft441_fwd(v_lds, Ar, Ai, c441, s441, ws + WS_SLOT(b), tid);
        __syncthreads();                         // all Vhat stores drained (vmcnt at barrier)
        if (tid == 0) {
            __threadfence();                     // device-scope writeback
            __hip_atomic_store(&flags[b], MAGIC, __ATOMIC_RELEASE, __HIP_MEMORY_SCOPE_AGENT);
        }
    }

    // ---------------- phase 2: flag-gated Horner + inverse FFT (blocks 1..NB-1) ----------------
    if (b >= 1) {
        // P = lambda^LB (all threads compute; only tid<221 uses)
        float pr = 1.0f, pi = 0.0f;
        {
            const float s = hwsin((float)(tid < 221 ? tid : 0) * INV441);
            const float c = hwcos((float)(tid < 221 ? tid : 0) * INV441);
            float lr = 0.5f*decay*(1.0f + c);
            float li = -0.5f*decay*s;
            float br = lr, bi = li;
            int e = LB;
            while (e) {
                if (e & 1) { float t = pr*br - pi*bi; pi = pr*bi + pi*br; pr = t; }
                float t2 = br*br - bi*bi; bi = 2.0f*br*bi; br = t2;
                e >>= 1;
            }
        }
        const int n = b;
        float sr = 0.f, si = 0.f;
        for (int base = 0; base < n; base += RD) {
            // wait for producers of this chunk (clamped indices; all < n)
            if (tid < RD) {
                int idx = base + tid; if (idx >= n) idx = n-1;
                while (__hip_atomic_load(&flags[idx], __ATOMIC_ACQUIRE,
                                         __HIP_MEMORY_SCOPE_AGENT) != MAGIC) { }
            }
            __syncthreads();
            __threadfence();                     // invalidate caches -> fresh Vhat reads
            if (tid < 221) {
                float cr[RD], ci[RD];
                #pragma unroll
                for (int d = 0; d < RD; ++d) {
                    int idx = base + d; if (idx >= n) idx = n-1;
                    cr[d] = ws[WS_SLOT(idx) + tid];
                    ci[d] = ws[WS_SLOT(idx) + 224 + tid];
                }
                #pragma unroll
                for (int d = 0; d < RD; ++d) {
                    if (base + d < n) {
                        float t1 = fmaf(pr, sr, fmaf(-pi, si, cr[d]));
                        si = fmaf(pr, si, fmaf(pi, sr, ci[d]));
                        sr = t1;
                    }
                }
            }
        }
        if (tid < 221) { SrF[tid] = sr; SiF[tid] = si; }
        __syncthreads();
        if (tid >= 221 && tid < 441) {           // conj extension: S[j] = conj(S[441-j])
            SrF[tid] =  SrF[441 - tid];
            SiF[tid] = -SiF[441 - tid];
        }
        __syncthreads();
        fft441_inv(SrF, SiF, Ar, Ai, c441, s441, e_lds, tid);
    }
    __syncthreads();

    // ---------------- phase 3: true recurrence from e_lds over staged tile + env/flush ----------------
    const float a_  = fabsf(envp[0]) + 1e-3f;
    const float sus = envp[1];
    const float rr  = fabsf(envp[2]) + 1e-3f;
    const float inv_a = 1.0f / a_;
    const float inv_r = 1.0f / rr;
    const float sg = sus * gain;
    const float T = t_in[N_SAMP - 1];

    float cur3[7];
    #pragma unroll
    for (int k = 0; k < 7; ++k)
        cur3[k] = act ? e_lds[7*j + k] : 0.f;

    auto compute_half = [&](auto PH) {
        constexpr int ph = decltype(PH)::value;
        if (w0) {
            unroll_for<HB>([&](auto I) {
                constexpr int il = decltype(I)::value;
                constexpr int i = ph*HB + il;
                float x[7];
                #pragma unroll
                for (int k = 0; k < 7; ++k) {
                    float fv = act ? fbL[i*WSZ + 7*j + k] : 0.f;
                    x[k] = fmaf(famt, fv, cur3[k]);
                }
                float x6p = __shfl(x[6], src);
                cur3[0] = d2 * (x[0] + x6p);
                #pragma unroll
                for (int k = 1; k < 7; ++k)
                    cur3[k] = d2 * (x[k] + x[k-1]);
                if (act) {
                    #pragma unroll
                    for (int k = 0; k < 7; ++k)
                        out_lds[il*WSZ + 7*j + k] = cur3[k];
                }
            });
        }
    };
    auto flush = [&](int ph) {
        const int s0 = (i0 + ph*HB) * WSZ;
        const float t_lo = (float)s0 * INV_SR;
        const float t_hi = (float)(s0 + HB*WSZ - 1) * INV_SR;
        const bool fastenv = (t_lo * inv_a >= 1.0f) &&
                             ((T - t_hi) * inv_r >= 1.0f) &&
                             (s0 + HB*WSZ <= FADE_START);
        if (fastenv) {
            for (int e = tid; e < HB*WSZ; e += 448)
                out[s0 + e] = out_lds[e] * sg;
        } else {
            for (int e = tid; e < HB*WSZ; e += 448) {
                const int idx = s0 + e;
                float tt = (float)idx * INV_SR;           // exact int->float: idx < 2^23
                float ca  = fminf(tt * inv_a, 1.0f);
                float crr = fminf(fmaxf((T - tt) * inv_r, 0.0f), 1.0f);
                float val = out_lds[e] * (ca * crr * sg);
                if (idx >= FADE_START) val *= fade[idx - FADE_START];
                out[idx] = val;
            }
        }
    };

    compute_half(std::integral_constant<int,0>{});
    __syncthreads();
    flush(0);
    __syncthreads();
    compute_half(std::integral_constant<int,1>{});
    __syncthreads();
    flush(1);
}

// ================== fallback path: proven r16 2-kernel pipeline ==================
__global__ __launch_bounds__(448, 1) void k_front(
    const float* __restrict__ fb, const float* __restrict__ h,
    const float* __restrict__ noise, const float* __restrict__ W1,
    const float* __restrict__ b1v, const float* __restrict__ W2,
    const float* __restrict__ b2v, const float* __restrict__ lpcut,
    float* __restrict__ ws)
{
    __shared__ __align__(16) float fbL[TILEF + 24];
    __shared__ __align__(16) float v_lds[448];
    __shared__ __align__(16) float Zr[441], Zi[441];
    __shared__ float c441[441], s441[441];
    const int b = blockIdx.x;
    const int tid = threadIdx.x;
    const bool w0 = tid < 64;
    const int j = tid;
    const bool act = w0 && (j < 63);
    const int i0 = b * LB;

    stage_tile7(fb + i0*WSZ, fbL, TILEF, tid);
    if (tid < 441) {
        float ph = (float)tid * INV441;
        c441[tid] = hwcos(ph);
        s441[tid] = hwsin(ph);
    }

    float lat[5];
    mlp_latents(h, W1, b1v, W2, b2v, tid & 63, lat);
    const float decay = fminf(fmaxf(lat[0]/10.0f + 0.9f, 0.9f), 0.999f);
    const float famt  = lat[3];
    const float d2 = 0.5f * decay;
    const int src = (j == 0) ? 62 : j - 1;

    float cur[7];
    #pragma unroll
    for (int k = 0; k < 7; ++k) cur[k] = 0.f;
    if (w0 && b == 0) {
        const float lpf = fminf(fmaxf(lat[1]*44100.0f/4.0f, 100.0f), 22049.0f);
        const float lpq = fminf(fmaxf(lat[2], 0.1f), 0.999f);
        const float f2  = lpcut[0];
        float xin[7], y1[7], y2[7];
        #pragma unroll
        for (int k = 0; k < 7; ++k) xin[k] = act ? noise[7*j + k] : 0.f;
        biquad_wave(xin, y1, lpf, lpq, j);
        biquad_wave(y1, y2, f2, 0.707f, j);
        #pragma unroll
        for (int k = 0; k < 7; ++k) {
            cur[k] = act ? y2[k] : 0.f;
            if (act) ws[WS_WT + 7*j + k] = y2[k];
        }
    }
    __syncthreads();

    if (w0) {
        unroll_for<LB>([&](auto I) {
            constexpr int i = decltype(I)::value;
            float x[7];
            #pragma unroll
            for (int k = 0; k < 7; ++k) {
                float fv = act ? fbL[i*WSZ + 7*j + k] : 0.f;
                x[k] = fmaf(famt, fv, cur[k]);
            }
            float x6p = __shfl(x[6], src);
            cur[0] = d2 * (x[0] + x6p);
            #pragma unroll
            for (int k = 1; k < 7; ++k)
                cur[k] = d2 * (x[k] + x[k-1]);
        });
        if (act) {
            #pragma unroll
            for (int k = 0; k < 7; ++k) v_lds[7*j + k] = cur[k];
        }
    }
    __syncthreads();

    fft441_fwd(v_lds, Zr, Zi, c441, s441, ws + WS_SLOT(b), tid);
}

__global__ __launch_bounds__(448, 1) void k_back(
    const float* __restrict__ fb, const float* __restrict__ h,
    const float* __restrict__ W1, const float* __restrict__ b1v,
    const float* __restrict__ W2, const float* __restrict__ b2v,
    const float* __restrict__ t_in, const float* __restrict__ envp,
    const float* __restrict__ fade, float* __restrict__ out,
    const float* __restrict__ ws)
{
    __shared__ __align__(16) float fbL[TILEF + 24];
    __shared__ float out_lds[HB*441];
    __shared__ __align__(16) float SrF[441], SiF[441];
    __shared__ __align__(16) float Hr[441], Hi[441];
    __shared__ __align__(16) float e_lds[448];
    __shared__ float c441[441], s441[441];
    const int b = blockIdx.x;
    const int tid = threadIdx.x;
    const bool w0 = tid < 64;
    const int j = tid;
    const bool act = w0 && (j < 63);
    const int i0 = b * LB;

    stage_tile7(fb + i0*WSZ, fbL, TILEF, tid);
    if (tid < 441) {
        float ph = (float)tid * INV441;
        c441[tid] = hwcos(ph);
        s441[tid] = hwsin(ph);
    }

    float lat[5];
    mlp_latents(h, W1, b1v, W2, b2v, tid & 63, lat);
    const float decay = fminf(fmaxf(lat[0]/10.0f + 0.9f, 0.9f), 0.999f);
    const float famt  = lat[3];
    const float gain  = lat[4];
    const float d2 = 0.5f * decay;
    const int src = (j == 0) ? 62 : j - 1;

    if (b == 0) {
        for (int m = tid; m < 441; m += 448) e_lds[m] = ws[WS_WT + m];
        __syncthreads();
    } else {
        if (tid < 221) {
            const float s = hwsin((float)tid * INV441);
            const float c = hwcos((float)tid * INV441);
            float lr = 0.5f*decay*(1.0f + c);
            float li = -0.5f*decay*s;
            float pr = 1.0f, pi = 0.0f, br = lr, bi = li;
            int e = LB;
            while (e) {
                if (e & 1) { float t = pr*br - pi*bi; pi = pr*bi + pi*br; pr = t; }
                float t2 = br*br - bi*bi; bi = 2.0f*br*bi; br = t2;
                e >>= 1;
            }
            const int n = b;
            float sr = 0.f, si = 0.f;
            for (int base = 0; base < n; base += RD) {
                float cr[RD], ci[RD];
                #pragma unroll
                for (int d = 0; d < RD; ++d) {
                    int idx = base + d; if (idx >= n) idx = n-1;
                    cr[d] = ws[WS_SLOT(idx) + tid];
                    ci[d] = ws[WS_SLOT(idx) + 224 + tid];
                }
                #pragma unroll
                for (int d = 0; d < RD; ++d) {
                    if (base + d < n) {
                        float t1 = fmaf(pr, sr, fmaf(-pi, si, cr[d]));
                        si = fmaf(pr, si, fmaf(pi, sr, ci[d]));
                        sr = t1;
                    }
                }
            }
            SrF[tid] = sr; SiF[tid] = si;
        }
        __syncthreads();
        if (tid >= 221 && tid < 441) {
            SrF[tid] =  SrF[441 - tid];
            SiF[tid] = -SiF[441 - tid];
        }
        __syncthreads();
        fft441_inv(SrF, SiF, Hr, Hi, c441, s441, e_lds, tid);
        __syncthreads();
    }

    const float a_  = fabsf(envp[0]) + 1e-3f;
    const float sus = envp[1];
    const float rr  = fabsf(envp[2]) + 1e-3f;
    const float inv_a = 1.0f / a_;
    const float inv_r = 1.0f / rr;
    const float sg = sus * gain;
    const float T = t_in[N_SAMP - 1];

    float cur[7];
    #pragma unroll
    for (int k = 0; k < 7; ++k)
        cur[k] = act ? e_lds[7*j + k] : 0.f;

    auto compute_half = [&](auto PH) {
        constexpr int ph = decltype(PH)::value;
        if (w0) {
            unroll_for<HB>([&](auto I) {
                constexpr int il = decltype(I)::value;
                constexpr int i = ph*HB + il;
                float x[7];
                #pragma unroll
                for (int k = 0; k < 7; ++k) {
                    float fv = act ? fbL[i*WSZ + 7*j + k] : 0.f;
                    x[k] = fmaf(famt, fv, cur[k]);
                }
                float x6p = __shfl(x[6], src);
                cur[0] = d2 * (x[0] + x6p);
                #pragma unroll
                for (int k = 1; k < 7; ++k)
                    cur[k] = d2 * (x[k] + x[k-1]);
                if (act) {
                    #pragma unroll
                    for (int k = 0; k < 7; ++k)
                        out_lds[il*WSZ + 7*j + k] = cur[k];
                }
            });
        }
    };
    auto flush = [&](int ph) {
        const int s0 = (i0 + ph*HB) * WSZ;
        const float t_lo = (float)s0 * INV_SR;
        const float t_hi = (float)(s0 + HB*WSZ - 1) * INV_SR;
        const bool fastenv = (t_lo * inv_a >= 1.0f) &&
                             ((T - t_hi) * inv_r >= 1.0f) &&
                             (s0 + HB*WSZ <= FADE_START);
        if (fastenv) {
            for (int e = tid; e < HB*WSZ; e += 448)
                out[s0 + e] = out_lds[e] * sg;
        } else {
            for (int e = tid; e < HB*WSZ; e += 448) {
                const int idx = s0 + e;
                float tt = (float)idx * INV_SR;
                float ca  = fminf(tt * inv_a, 1.0f);
                float crr = fminf(fmaxf((T - tt) * inv_r, 0.0f), 1.0f);
                float val = out_lds[e] * (ca * crr * sg);
                if (idx >= FADE_START) val *= fade[idx - FADE_START];
                out[idx] = val;
            }
        }
    };

    compute_half(std::integral_constant<int,0>{});
    __syncthreads();
    flush(0);
    __syncthreads();
    compute_half(std::integral_constant<int,1>{});
    __syncthreads();
    flush(1);
}

// ---------------- fallback: fully sequential single block (no workspace) ----------
__global__ __launch_bounds__(448) void k_naive(
    const float* __restrict__ fb, const float* __restrict__ h,
    const float* __restrict__ t_in, const float* __restrict__ noise,
    const float* __restrict__ W1, const float* __restrict__ b1v,
    const float* __restrict__ W2, const float* __restrict__ b2v,
    const float* __restrict__ lpcut, const float* __restrict__ envp,
    const float* __restrict__ fade, float* __restrict__ out)
{
    __shared__ float hid[128];
    __shared__ float lat[5];
    __shared__ float wt[WSZ];
    __shared__ float buf[2][448];
    const int j = threadIdx.x;
    if (j < 128) {
        float acc = b1v[j];
        #pragma unroll
        for (int i = 0; i < 9; ++i) acc = acc + h[i] * W1[i*128 + j];
        hid[j] = fmaxf(acc, 0.0f);
    }
    __syncthreads();
    if (j < 5) {
        float a = b2v[j];
        for (int k = 0; k < 128; ++k) a = a + hid[k] * W2[k*5 + j];
        lat[j] = fmaxf(a, 0.0f);
    }
    __syncthreads();
    if (j == 0) {
        float lpf = fminf(fmaxf(lat[1]*44100.0f/4.0f, 100.0f), 22049.0f);
        float lpq = fminf(fmaxf(lat[2], 0.1f), 0.999f);
        run_biquads(noise, lpf, lpq, lpcut[0], wt);
    }
    __syncthreads();
    const float decay = fminf(fmaxf(lat[0]/10.0f + 0.9f, 0.9f), 0.999f);
    const float famt = lat[3];
    const float gain = lat[4];
    const float d2 = 0.5f * decay;
    const float a_  = fabsf(envp[0]) + 1e-3f;
    const float sus = envp[1];
    const float rr  = fabsf(envp[2]) + 1e-3f;
    const float inv_a = 1.0f / a_, inv_r = 1.0f / rr;
    const float T = t_in[N_SAMP - 1];
    const bool act = j < WSZ;
    const int jm1 = (j == 0) ? (WSZ - 1) : (j - 1);
    float cur = act ? wt[j] : 0.0f;
    for (int i = 0; i < NC; ++i) {
        float x = cur + famt * (act ? fb[i*WSZ + j] : 0.0f);
        buf[i&1][j] = x;
        __syncthreads();
        cur = d2 * (x + buf[i&1][jm1]);
        const int idx = i*WSZ + j;
        float val = cur;
        if (idx >= FADE_START) val *= fade[idx - FADE_START];
        float tt = act ? t_in[idx] : 0.0f;
        float ca  = fminf(fmaxf(tt * inv_a, 0.0f), 1.0f);
        float cr2 = fminf(fmaxf((T - tt) * inv_r, 0.0f), 1.0f);
        val = val * (ca * cr2 * sus) * gain;
        if (act) out[idx] = val;
    }
}

extern "C" void kernel_launch(void* const* d_in, const int* in_sizes, int n_in,
                              void* d_out, int out_size, void* d_ws, size_t ws_size,
                              hipStream_t stream) {
    const float* fb   = (const float*)d_in[0];
    const float* h    = (const float*)d_in[1];
    const float* t    = (const float*)d_in[2];
    const float* nz   = (const float*)d_in[3];
    const float* W1   = (const float*)d_in[4];
    const float* b1v  = (const float*)d_in[5];
    const float* W2   = (const float*)d_in[6];
    const float* b2v  = (const float*)d_in[7];
    const float* lpc  = (const float*)d_in[8];
    const float* envp = (const float*)d_in[9];
    const float* fade = (const float*)d_in[10];
    float* out = (float*)d_out;
    float* ws  = (float*)d_ws;

    if (ws_size < WS_NEED) {
        k_naive<<<1, 448, 0, stream>>>(fb, h, t, nz, W1, b1v, W2, b2v, lpc, envp, fade, out);
        return;
    }

    void* args[] = {
        (void*)&fb, (void*)&h, (void*)&nz, (void*)&W1, (void*)&b1v,
        (void*)&W2, (void*)&b2v, (void*)&lpc, (void*)&t, (void*)&envp,
        (void*)&fade, (void*)&out, (void*)&ws
    };
    hipError_t err = hipLaunchCooperativeKernel((const void*)k_all, dim3(NB), dim3(448),
                                                args, 0, stream);
    if (err != hipSuccess) {
        // fallback: proven r16 2-kernel path (identical output)
        k_front<<<NB-1, 448, 0, stream>>>(fb, h, nz, W1, b1v, W2, b2v, lpc, ws);
        k_back <<<NB,   448, 0, stream>>>(fb, h, W1, b1v, W2, b2v, t, envp, fade, out, ws);
    }
}

// Round 18
// 45.343 us; speedup vs baseline: 5.0845x; 5.0845x over previous
//
#include <hip/hip_runtime.h>
#include <utility>

#define N_SAMP   4410000
#define WSZ      441
#define NC       10000
#define NB       250
#define LB       40           // NB*LB == NC
#define HB       20           // half-block flush granularity
#define TILEF    (LB*WSZ)     // 17640 floats = per-block fb tile (70.6 KB)
#define RD       16           // Horner prefetch ring depth
#define TWO_PI_F 6.28318530717958647692f
#define FADE_START (N_SAMP - 256)
#define INV_SR   (1.0f/44100.0f)
#define INV441   (1.0f/441.0f)

// workspace layout (floats)
#define WS_WT   0                          // 441 wavetable (padded 448)
#define WS_SLOT(a) (448 + (a)*448)         // a = 0..NB-2: Vhat_a ([0..220]=Re, [224..444]=Im)
#define WS_NEED ((size_t)(448 + (NB-1)*448) * sizeof(float))

static_assert(NB * LB == NC, "block decomposition");
static_assert(LB == 2*HB, "two flush phases");

// ---- compile-time loop unroll (forces static indices -> registers, rule #20) ----
template <class F, int... Is>
__device__ __forceinline__ void unroll_impl(F f, std::integer_sequence<int, Is...>) {
    (f(std::integral_constant<int, Is>{}), ...);
}
template <int N, class F>
__device__ __forceinline__ void unroll_for(F f) {
    unroll_impl(f, std::make_integer_sequence<int, N>{});
}

// hardware trig: v_sin_f32/v_cos_f32 — input in REVOLUTIONS (sin/cos(2*pi*x)).
__device__ __forceinline__ float hwsin(float rev) { return __builtin_amdgcn_sinf(rev); }
__device__ __forceinline__ float hwcos(float rev) { return __builtin_amdgcn_cosf(rev); }

// async global->LDS: lane l copies 16B from its gsrc to ldsbase + l*16 (wave-uniform base).
__device__ __forceinline__ void gl2lds16(const float* gsrc_lane, float* lds_base_uniform) {
    __builtin_amdgcn_global_load_lds(
        (const __attribute__((address_space(1))) void*)gsrc_lane,
        (__attribute__((address_space(3))) void*)lds_base_uniform,
        16, 0, 0);
}

// stage nfloats from g to l using 7 waves (448 threads); caller must __syncthreads() after.
__device__ __forceinline__ void stage_tile7(const float* __restrict__ g,
                                            float* __restrict__ l,
                                            int nfloats, int tid) {
    const int wave = tid >> 6, lane = tid & 63;
    const int nfull = nfloats >> 8;              // 256-float (1 KiB) chunks
    for (int c = wave; c < nfull; c += 7)
        gl2lds16(g + (c << 8) + lane*4, l + (c << 8));
    const int rem = nfloats & 255;
    if (rem && wave == 0 && lane*4 < rem) {
        const int base = nfull << 8;
        gl2lds16(g + base + lane*4, l + base);
    }
}

__device__ __forceinline__ void bq_coefs(float f, float q,
    float& b0, float& b1, float& b2, float& a1, float& a2)
{
    float w0 = TWO_PI_F * f / 44100.0f;
    float cw = cosf(w0), sw = sinf(w0);
    float al = sw / (2.0f * q);
    float a0 = 1.0f + al;
    b0 = ((1.0f - cw) * 0.5f) / a0;
    b1 = (1.0f - cw) / a0;
    b2 = ((1.0f - cw) * 0.5f) / a0;
    a1 = (-2.0f * cw) / a0;
    a2 = (1.0f - al) / a0;
}

// serial biquad pair (fallback kernel only)
__device__ __forceinline__ void run_biquads(const float* __restrict__ noise,
    float lpf, float lpq, float f2, float* dst)
{
    float c10,c11,c12,c13,c14, c20,c21,c22,c23,c24;
    bq_coefs(lpf, lpq, c10,c11,c12,c13,c14);
    bq_coefs(f2, 0.707f, c20,c21,c22,c23,c24);
    float s11=0.f,s12=0.f,s21=0.f,s22=0.f;
    for (int m = 0; m < WSZ; ++m) {
        float x  = noise[m];
        float y1 = c10*x + s11;
        s11 = c11*x - c13*y1 + s12;
        s12 = c12*x - c14*y1;
        float y2 = c20*y1 + s21;
        s21 = c21*y1 - c23*y2 + s22;
        s22 = c22*y1 - c24*y2;
        dst[m] = y2;
    }
}

// redundant per-wave MLP: lane computes hid cols lane, lane+64; shfl_xor reduce -> lat[5]
__device__ __forceinline__ void mlp_latents(
    const float* __restrict__ h, const float* __restrict__ W1,
    const float* __restrict__ b1v, const float* __restrict__ W2,
    const float* __restrict__ b2v, int lane, float lat[5])
{
    float hc0 = b1v[lane], hc1 = b1v[lane + 64];
    #pragma unroll
    for (int i = 0; i < 9; ++i) {
        float hv = h[i];
        hc0 = fmaf(hv, W1[i*128 + lane], hc0);
        hc1 = fmaf(hv, W1[i*128 + lane + 64], hc1);
    }
    hc0 = fmaxf(hc0, 0.f); hc1 = fmaxf(hc1, 0.f);
    float part[5];
    #pragma unroll
    for (int m = 0; m < 5; ++m)
        part[m] = fmaf(hc0, W2[lane*5 + m], hc1 * W2[(lane+64)*5 + m]);
    #pragma unroll
    for (int off = 32; off > 0; off >>= 1) {
        #pragma unroll
        for (int m = 0; m < 5; ++m)
            part[m] += __shfl_xor(part[m], off);
    }
    #pragma unroll
    for (int m = 0; m < 5; ++m)
        lat[m] = fmaxf(part[m] + b2v[m], 0.f);
}

// wave-parallel biquad over 441 samples: lane l holds positions 7l..7l+6 (Kogge-Stone affine scan)
__device__ __forceinline__ void biquad_wave(const float xin[7], float yout[7],
    float f, float q, int l)
{
    float b0,b1,b2,a1,a2;
    bq_coefs(f, q, b0,b1,b2,a1,a2);
    const float t1c = b1 - a1*b0;
    const float t2c = b2 - a2*b0;
    float m00=1.f,m01=0.f,m10=0.f,m11=1.f;
    float cv0=0.f, cv1=0.f;
    #pragma unroll
    for (int k = 0; k < 7; ++k) {
        float x = xin[k];
        float n0 = -a1*cv0 + cv1 + t1c*x;
        float n1 = -a2*cv0 + t2c*x;
        cv0 = n0; cv1 = n1;
        float r00 = -a1*m00 + m10, r01 = -a1*m01 + m11;
        float r10 = -a2*m00,       r11 = -a2*m01;
        m00=r00; m01=r01; m10=r10; m11=r11;
    }
    #pragma unroll
    for (int d = 1; d < 64; d <<= 1) {
        int srcl = l - d; int s2 = srcl < 0 ? 0 : srcl;
        float pm00=__shfl(m00,s2), pm01=__shfl(m01,s2);
        float pm10=__shfl(m10,s2), pm11=__shfl(m11,s2);
        float pc0=__shfl(cv0,s2), pc1=__shfl(cv1,s2);
        if (srcl >= 0) {
            float nc0 = m00*pc0 + m01*pc1 + cv0;
            float nc1 = m10*pc0 + m11*pc1 + cv1;
            float n00 = m00*pm00 + m01*pm10;
            float n01 = m00*pm01 + m01*pm11;
            float n10 = m10*pm00 + m11*pm10;
            float n11 = m10*pm01 + m11*pm11;
            m00=n00; m01=n01; m10=n10; m11=n11; cv0=nc0; cv1=nc1;
        }
    }
    int esrc = (l == 0) ? 0 : l - 1;
    float e0 = __shfl(cv0, esrc);
    float e1 = __shfl(cv1, esrc);
    float s1  = (l == 0) ? 0.f : e0;
    float s2v = (l == 0) ? 0.f : e1;
    #pragma unroll
    for (int k = 0; k < 7; ++k) {
        float x = xin[k];
        float y = b0*x + s1;
        float ns1 = b1*x - a1*y + s2v;
        s2v = b2*x - a2*y;
        s1 = ns1;
        yout[k] = y;
    }
}

// ---------- 441-pt forward FFT (21x21 Cooley-Tukey), real input in v, modes 0..220 -> ws slot ----------
__device__ __forceinline__ void fft441_fwd(const float* v, float* Zr, float* Zi,
    const float* c441, const float* s441, float* ws_slot, int tid)
{
    if (tid < 441) {
        const int bq = tid / 21, c = tid - 21*bq;
        float yr = 0.f, yi = 0.f;
        int pm = 0;                                // (a*c) % 21
        #pragma unroll
        for (int a = 0; a < 21; ++a) {
            float x = v[21*a + bq];
            float cc = c441[21*pm], ss = s441[21*pm];
            yr = fmaf(x,  cc, yr);
            yi = fmaf(-x, ss, yi);
            pm += c; if (pm >= 21) pm -= 21;
        }
        const int bc = bq * c;                     // <= 400 < 441
        float cB = c441[bc], sB = s441[bc];
        Zr[c*21 + bq] = yr*cB + yi*sB;             // Z = Y * (cB - i sB)
        Zi[c*21 + bq] = yi*cB - yr*sB;
    }
    __syncthreads();
    if (tid < 441) {
        const int c = tid / 21, d = tid - 21*c;
        float xr = 0.f, xi = 0.f;
        int pm = 0;                                // (b*d) % 21
        const float* zr = Zr + c*21;
        const float* zi = Zi + c*21;
        #pragma unroll
        for (int bq = 0; bq < 21; ++bq) {
            float cc = c441[21*pm], ss = s441[21*pm];
            float gr = zr[bq], gi = zi[bq];
            xr = fmaf(gr, cc, fmaf(gi,  ss, xr));  // X += Z * (cc - i ss)
            xi = fmaf(gi, cc, fmaf(-gr, ss, xi));
            pm += d; if (pm >= 21) pm -= 21;
        }
        const int jm = c + 21*d;
        if (jm < 221) {
            ws_slot[jm]       = xr;
            ws_slot[224 + jm] = xi;
        }
    }
}

// ---------- 441-pt inverse FFT: full-spectrum S (conj-extended) -> real e_lds; scaled 1/441 ----------
__device__ __forceinline__ void fft441_inv(const float* SrF, const float* SiF,
    float* Hr, float* Hi, const float* c441, const float* s441,
    float* e_lds, int tid)
{
    if (tid < 441) {
        const int bq = tid / 21, c = tid - 21*bq;
        float gr = 0.f, gi = 0.f;
        int pm = 0;                                // (a*c) % 21
        #pragma unroll
        for (int a = 0; a < 21; ++a) {
            float sr = SrF[21*a + bq], si = SiF[21*a + bq];
            float cc = c441[21*pm], ss = s441[21*pm];
            gr = fmaf(sr, cc, fmaf(-si, ss, gr));  // G += S * (cc + i ss)
            gi = fmaf(sr, ss, fmaf( si, cc, gi));
            pm += c; if (pm >= 21) pm -= 21;
        }
        const int bc = bq * c;
        float cB = c441[bc], sB = s441[bc];
        Hr[c*21 + bq] = gr*cB - gi*sB;             // H = G * (cB + i sB)
        Hi[c*21 + bq] = gr*sB + gi*cB;
    }
    __syncthreads();
    if (tid < 441) {
        const int c = tid / 21, d = tid - 21*c;
        float acc = 0.f;
        int pm = 0;                                // (b*d) % 21
        const float* hr = Hr + c*21;
        const float* hi = Hi + c*21;
        #pragma unroll
        for (int bq = 0; bq < 21; ++bq) {
            float cc = c441[21*pm], ss = s441[21*pm];
            acc = fmaf(hr[bq], cc, fmaf(-hi[bq], ss, acc));  // Re(H * (cc + i ss))
            pm += d; if (pm >= 21) pm -= 21;
        }
        e_lds[c + 21*d] = acc * (1.0f/441.0f);
    }
}

// ============ kernel 1: whole-tile staging + local recurrence + forward FFT ============
__global__ __launch_bounds__(448, 1) void k_front(
    const float* __restrict__ fb, const float* __restrict__ h,
    const float* __restrict__ noise, const float* __restrict__ W1,
    const float* __restrict__ b1v, const float* __restrict__ W2,
    const float* __restrict__ b2v, const float* __restrict__ lpcut,
    float* __restrict__ ws)
{
    __shared__ __align__(16) float fbL[TILEF + 24];    // 70.7 KB
    __shared__ __align__(16) float v_lds[448];
    __shared__ __align__(16) float Zr[441], Zi[441];
    __shared__ float c441[441], s441[441];
    const int b = blockIdx.x;              // 0..NB-2
    const int tid = threadIdx.x;
    const bool w0 = tid < 64;
    const int j = tid;
    const bool act = w0 && (j < 63);
    const int i0 = b * LB;

    stage_tile7(fb + i0*WSZ, fbL, TILEF, tid);   // issue first; drains at 1st barrier
    if (tid < 441) {
        float ph = (float)tid * INV441;
        c441[tid] = hwcos(ph);
        s441[tid] = hwsin(ph);
    }

    float lat[5];
    mlp_latents(h, W1, b1v, W2, b2v, tid & 63, lat);
    const float decay = fminf(fmaxf(lat[0]/10.0f + 0.9f, 0.9f), 0.999f);
    const float famt  = lat[3];
    const float d2 = 0.5f * decay;
    const int src = (j == 0) ? 62 : j - 1;

    float cur[7];
    #pragma unroll
    for (int k = 0; k < 7; ++k) cur[k] = 0.f;
    if (w0 && b == 0) {
        const float lpf = fminf(fmaxf(lat[1]*44100.0f/4.0f, 100.0f), 22049.0f);
        const float lpq = fminf(fmaxf(lat[2], 0.1f), 0.999f);
        const float f2  = lpcut[0];
        float xin[7], y1[7], y2[7];
        #pragma unroll
        for (int k = 0; k < 7; ++k) xin[k] = act ? noise[7*j + k] : 0.f;
        biquad_wave(xin, y1, lpf, lpq, j);
        biquad_wave(y1, y2, f2, 0.707f, j);
        #pragma unroll
        for (int k = 0; k < 7; ++k) {
            cur[k] = act ? y2[k] : 0.f;
            if (act) ws[WS_WT + 7*j + k] = y2[k];
        }
    }
    __syncthreads();                           // staging drained; tables ready

    if (w0) {
        unroll_for<LB>([&](auto I) {
            constexpr int i = decltype(I)::value;
            float x[7];
            #pragma unroll
            for (int k = 0; k < 7; ++k) {
                float fv = act ? fbL[i*WSZ + 7*j + k] : 0.f;
                x[k] = fmaf(famt, fv, cur[k]);
            }
            float x6p = __shfl(x[6], src);     // pos 7j-1; lane0 <- lane62 (pos 440)
            cur[0] = d2 * (x[0] + x6p);
            #pragma unroll
            for (int k = 1; k < 7; ++k)
                cur[k] = d2 * (x[k] + x[k-1]);
        });
        if (act) {
            #pragma unroll
            for (int k = 0; k < 7; ++k) v_lds[7*j + k] = cur[k];
        }
    }
    __syncthreads();

    fft441_fwd(v_lds, Zr, Zi, c441, s441, ws + WS_SLOT(b), tid);
}

// ============ kernel 2: staging + per-block register Horner + inverse FFT + recurrence + env/flush ============
__global__ __launch_bounds__(448, 1) void k_back(
    const float* __restrict__ fb, const float* __restrict__ h,
    const float* __restrict__ W1, const float* __restrict__ b1v,
    const float* __restrict__ W2, const float* __restrict__ b2v,
    const float* __restrict__ t_in, const float* __restrict__ envp,
    const float* __restrict__ fade, float* __restrict__ out,
    const float* __restrict__ ws)
{
    __shared__ __align__(16) float fbL[TILEF + 24];    // 70.7 KB
    __shared__ float out_lds[HB*441];                  // 35.3 KB
    __shared__ __align__(16) float SrF[441], SiF[441];
    __shared__ __align__(16) float Hr[441], Hi[441];
    __shared__ __align__(16) float e_lds[448];
    __shared__ float c441[441], s441[441];
    const int b = blockIdx.x;                          // 0..NB-1
    const int tid = threadIdx.x;
    const bool w0 = tid < 64;
    const int j = tid;
    const bool act = w0 && (j < 63);
    const int i0 = b * LB;

    stage_tile7(fb + i0*WSZ, fbL, TILEF, tid);   // issue early; drains at barriers below
    if (tid < 441) {
        float ph = (float)tid * INV441;
        c441[tid] = hwcos(ph);
        s441[tid] = hwsin(ph);
    }

    float lat[5];
    mlp_latents(h, W1, b1v, W2, b2v, tid & 63, lat);
    const float decay = fminf(fmaxf(lat[0]/10.0f + 0.9f, 0.9f), 0.999f);
    const float famt  = lat[3];
    const float gain  = lat[4];
    const float d2 = 0.5f * decay;
    const int src = (j == 0) ? 62 : j - 1;

    if (b == 0) {
        for (int m = tid; m < 441; m += 448) e_lds[m] = ws[WS_WT + m];
        __syncthreads();
    } else {
        if (tid < 221) {
            // P = lambda^LB; lambda_j = d/2 (1 + e^{-2 pi i j/441})
            const float s = hwsin((float)tid * INV441);
            const float c = hwcos((float)tid * INV441);
            float lr = 0.5f*decay*(1.0f + c);
            float li = -0.5f*decay*s;
            float pr = 1.0f, pi = 0.0f, br = lr, bi = li;
            int e = LB;
            while (e) {
                if (e & 1) { float t = pr*br - pi*bi; pi = pr*bi + pi*br; pr = t; }
                float t2 = br*br - bi*bi; bi = 2.0f*br*bi; br = t2;
                e >>= 1;
            }
            // Horner over own predecessors, register ring RD deep (ws is L3-hot, reads coalesced)
            const int n = b;
            float sr = 0.f, si = 0.f;
            float cr[RD], ci[RD];
            #pragma unroll
            for (int d = 0; d < RD; ++d) {
                int idx = (d < n) ? d : n-1;
                cr[d] = ws[WS_SLOT(idx) + tid];
                ci[d] = ws[WS_SLOT(idx) + 224 + tid];
            }
            for (int base = 0; base < n; base += RD) {
                float nr[RD], ni[RD];
                #pragma unroll
                for (int d = 0; d < RD; ++d) {
                    int idx = base + RD + d; if (idx >= n) idx = n-1;
                    nr[d] = ws[WS_SLOT(idx) + tid];
                    ni[d] = ws[WS_SLOT(idx) + 224 + tid];
                }
                #pragma unroll
                for (int d = 0; d < RD; ++d) {
                    if (base + d < n) {
                        float t1 = fmaf(pr, sr, fmaf(-pi, si, cr[d]));
                        si = fmaf(pr, si, fmaf(pi, sr, ci[d]));
                        sr = t1;
                    }
                }
                #pragma unroll
                for (int d = 0; d < RD; ++d) { cr[d] = nr[d]; ci[d] = ni[d]; }
            }
            SrF[tid] = sr; SiF[tid] = si;
        }
        __syncthreads();
        if (tid >= 221 && tid < 441) {          // conj extension: S[j] = conj(S[441-j])
            SrF[tid] =  SrF[441 - tid];
            SiF[tid] = -SiF[441 - tid];
        }
        __syncthreads();
        fft441_inv(SrF, SiF, Hr, Hi, c441, s441, e_lds, tid);
        __syncthreads();
    }

    const float a_  = fabsf(envp[0]) + 1e-3f;
    const float sus = envp[1];
    const float rr  = fabsf(envp[2]) + 1e-3f;
    const float inv_a = 1.0f / a_;
    const float inv_r = 1.0f / rr;
    const float sg = sus * gain;
    const float T = t_in[N_SAMP - 1];

    float cur[7];
    #pragma unroll
    for (int k = 0; k < 7; ++k)
        cur[k] = act ? e_lds[7*j + k] : 0.f;

    auto compute_half = [&](auto PH) {
        constexpr int ph = decltype(PH)::value;
        if (w0) {
            unroll_for<HB>([&](auto I) {
                constexpr int il = decltype(I)::value;
                constexpr int i = ph*HB + il;
                float x[7];
                #pragma unroll
                for (int k = 0; k < 7; ++k) {
                    float fv = act ? fbL[i*WSZ + 7*j + k] : 0.f;
                    x[k] = fmaf(famt, fv, cur[k]);
                }
                float x6p = __shfl(x[6], src);
                cur[0] = d2 * (x[0] + x6p);
                #pragma unroll
                for (int k = 1; k < 7; ++k)
                    cur[k] = d2 * (x[k] + x[k-1]);
                if (act) {
                    #pragma unroll
                    for (int k = 0; k < 7; ++k)
                        out_lds[il*WSZ + 7*j + k] = cur[k];
                }
            });
        }
    };
    auto flush = [&](int ph) {
        const int s0 = (i0 + ph*HB) * WSZ;
        const float t_lo = (float)s0 * INV_SR;
        const float t_hi = (float)(s0 + HB*WSZ - 1) * INV_SR;
        const bool fastenv = (t_lo * inv_a >= 1.0f) &&
                             ((T - t_hi) * inv_r >= 1.0f) &&
                             (s0 + HB*WSZ <= FADE_START);
        if (fastenv) {
            for (int e = tid; e < HB*WSZ; e += 448)
                out[s0 + e] = out_lds[e] * sg;
        } else {
            for (int e = tid; e < HB*WSZ; e += 448) {
                const int idx = s0 + e;
                float tt = (float)idx * INV_SR;           // exact int->float: idx < 2^23
                float ca  = fminf(tt * inv_a, 1.0f);
                float crr = fminf(fmaxf((T - tt) * inv_r, 0.0f), 1.0f);
                float val = out_lds[e] * (ca * crr * sg);
                if (idx >= FADE_START) val *= fade[idx - FADE_START];
                out[idx] = val;
            }
        }
    };

    compute_half(std::integral_constant<int,0>{});
    __syncthreads();
    flush(0);
    __syncthreads();
    compute_half(std::integral_constant<int,1>{});
    __syncthreads();
    flush(1);
}

// ---------------- fallback: fully sequential single block (no workspace) ----------
__global__ __launch_bounds__(448) void k_naive(
    const float* __restrict__ fb, const float* __restrict__ h,
    const float* __restrict__ t_in, const float* __restrict__ noise,
    const float* __restrict__ W1, const float* __restrict__ b1v,
    const float* __restrict__ W2, const float* __restrict__ b2v,
    const float* __restrict__ lpcut, const float* __restrict__ envp,
    const float* __restrict__ fade, float* __restrict__ out)
{
    __shared__ float hid[128];
    __shared__ float lat[5];
    __shared__ float wt[WSZ];
    __shared__ float buf[2][448];
    const int j = threadIdx.x;
    if (j < 128) {
        float acc = b1v[j];
        #pragma unroll
        for (int i = 0; i < 9; ++i) acc = acc + h[i] * W1[i*128 + j];
        hid[j] = fmaxf(acc, 0.0f);
    }
    __syncthreads();
    if (j < 5) {
        float a = b2v[j];
        for (int k = 0; k < 128; ++k) a = a + hid[k] * W2[k*5 + j];
        lat[j] = fmaxf(a, 0.0f);
    }
    __syncthreads();
    if (j == 0) {
        float lpf = fminf(fmaxf(lat[1]*44100.0f/4.0f, 100.0f), 22049.0f);
        float lpq = fminf(fmaxf(lat[2], 0.1f), 0.999f);
        run_biquads(noise, lpf, lpq, lpcut[0], wt);
    }
    __syncthreads();
    const float decay = fminf(fmaxf(lat[0]/10.0f + 0.9f, 0.9f), 0.999f);
    const float famt = lat[3];
    const float gain = lat[4];
    const float d2 = 0.5f * decay;
    const float a_  = fabsf(envp[0]) + 1e-3f;
    const float sus = envp[1];
    const float rr  = fabsf(envp[2]) + 1e-3f;
    const float inv_a = 1.0f / a_, inv_r = 1.0f / rr;
    const float T = t_in[N_SAMP - 1];
    const bool act = j < WSZ;
    const int jm1 = (j == 0) ? (WSZ - 1) : (j - 1);
    float cur = act ? wt[j] : 0.0f;
    for (int i = 0; i < NC; ++i) {
        float x = cur + famt * (act ? fb[i*WSZ + j] : 0.0f);
        buf[i&1][j] = x;
        __syncthreads();
        cur = d2 * (x + buf[i&1][jm1]);
        const int idx = i*WSZ + j;
        float val = cur;
        if (idx >= FADE_START) val *= fade[idx - FADE_START];
        float tt = act ? t_in[idx] : 0.0f;
        float ca  = fminf(fmaxf(tt * inv_a, 0.0f), 1.0f);
        float cr2 = fminf(fmaxf((T - tt) * inv_r, 0.0f), 1.0f);
        val = val * (ca * cr2 * sus) * gain;
        if (act) out[idx] = val;
    }
}

extern "C" void kernel_launch(void* const* d_in, const int* in_sizes, int n_in,
                              void* d_out, int out_size, void* d_ws, size_t ws_size,
                              hipStream_t stream) {
    const float* fb   = (const float*)d_in[0];
    const float* h    = (const float*)d_in[1];
    const float* t    = (const float*)d_in[2];
    const float* nz   = (const float*)d_in[3];
    const float* W1   = (const float*)d_in[4];
    const float* b1v  = (const float*)d_in[5];
    const float* W2   = (const float*)d_in[6];
    const float* b2v  = (const float*)d_in[7];
    const float* lpc  = (const float*)d_in[8];
    const float* envp = (const float*)d_in[9];
    const float* fade = (const float*)d_in[10];
    float* out = (float*)d_out;
    float* ws  = (float*)d_ws;

    if (ws_size < WS_NEED) {
        k_naive<<<1, 448, 0, stream>>>(fb, h, t, nz, W1, b1v, W2, b2v, lpc, envp, fade, out);
        return;
    }
    k_front<<<NB-1, 448, 0, stream>>>(fb, h, nz, W1, b1v, W2, b2v, lpc, ws);
    k_back <<<NB,   448, 0, stream>>>(fb, h, W1, b1v, W2, b2v, t, envp, fade, out, ws);
}